// Round 2
// baseline (1611.901 us; speedup 1.0000x reference)
//
#include <hip/hip_runtime.h>

#define DM    128
#define NHEAD 2
#define HIDC  64
#define OUTC  32
#define NG    64
#define EPS   1e-5f

// ---------------------------------------------------------------------------
// GEMM per node row: H = X @ W  (+ optional S = X @ Wskip + bskip)
// plus per-head attention dots a_src/a_dst via wave reduction.
// block = 128 threads (2 waves of 64; wave id == head id), grid = N
// ---------------------------------------------------------------------------
__global__ void gemm_attn_kernel(const float* __restrict__ X,
                                 const float* __restrict__ W,
                                 const float* __restrict__ Wskip,   // nullable
                                 const float* __restrict__ bskip,   // nullable
                                 const float* __restrict__ att_src,
                                 const float* __restrict__ att_dst,
                                 float* __restrict__ H,
                                 float* __restrict__ S,             // nullable
                                 float* __restrict__ a_src,
                                 float* __restrict__ a_dst)
{
    __shared__ float xr[DM];
    const int n = blockIdx.x;
    const int t = threadIdx.x;
    xr[t] = X[n * DM + t];
    __syncthreads();

    float acc = 0.f, accs = 0.f;
    if (Wskip) {
#pragma unroll
        for (int k = 0; k < DM; ++k) {
            float xv = xr[k];
            acc  += xv * W[k * DM + t];
            accs += xv * Wskip[k * DM + t];
        }
    } else {
#pragma unroll
        for (int k = 0; k < DM; ++k) acc += xr[k] * W[k * DM + t];
    }
    H[n * DM + t] = acc;
    if (S) S[n * DM + t] = accs + bskip[t];

    const int lane = t & 63, head = t >> 6;
    float vs = acc * att_src[head * HIDC + lane];
    float vd = acc * att_dst[head * HIDC + lane];
#pragma unroll
    for (int off = 32; off; off >>= 1) {
        vs += __shfl_down(vs, off);
        vd += __shfl_down(vd, off);
    }
    if (lane == 0) {
        a_src[n * NHEAD + head] = vs;
        a_dst[n * NHEAD + head] = vd;
    }
}

// ---------------------------------------------------------------------------
// Edge pass 1: ee = exp(leaky_relu(a_src[s]+a_dst[d])); denom[d] += ee
// one thread per (edge, head). Self loops: e >= E -> s = d = e - E.
// (segment_max subtraction skipped: alpha = ee/denom is mathematically
//  identical and logits are O(5), fp32-safe.)
// ---------------------------------------------------------------------------
__global__ void edge_logits_kernel(const int* __restrict__ ei, int E, int Ep,
                                   const float* __restrict__ a_src,
                                   const float* __restrict__ a_dst,
                                   float* __restrict__ ebuf,
                                   float* __restrict__ denom)
{
    int idx = blockIdx.x * blockDim.x + threadIdx.x;
    if (idx >= Ep * NHEAD) return;
    int e = idx >> 1, head = idx & 1;
    int s, d;
    if (e < E) { s = ei[e]; d = ei[E + e]; } else { s = e - E; d = s; }
    float v = a_src[s * NHEAD + head] + a_dst[d * NHEAD + head];
    v = v > 0.f ? v : 0.2f * v;
    float ee = expf(v);
    ebuf[idx] = ee;
    atomicAdd(&denom[d * NHEAD + head], ee);
}

// ---------------------------------------------------------------------------
// Edge pass 2: agg[d, c] += H[s, c] * (ee / denom[d])
// one thread per (edge, channel); 128 consecutive threads = one edge.
// ---------------------------------------------------------------------------
__global__ void edge_msg_kernel(const int* __restrict__ ei, int E, int Ep,
                                const float* __restrict__ H,
                                const float* __restrict__ ebuf,
                                const float* __restrict__ denom,
                                float* __restrict__ agg)
{
    int idx = blockIdx.x * blockDim.x + threadIdx.x;
    if (idx >= Ep * DM) return;
    int e = idx >> 7, c = idx & (DM - 1);
    int s, d;
    if (e < E) { s = ei[e]; d = ei[E + e]; } else { s = e - E; d = s; }
    int head = c >> 6;
    float alpha = ebuf[e * NHEAD + head] / denom[d * NHEAD + head];
    atomicAdd(&agg[d * DM + c], H[s * DM + c] * alpha);
}

// ---------------------------------------------------------------------------
// LayerNorm row kernel: v = agg + bias (+ res); y = elu(LN(v)); out = y (+ skip)
// block = 128 (2 waves), grid = N. In-place safe (each thread owns its elem).
// ---------------------------------------------------------------------------
__global__ void ln_kernel(const float* __restrict__ agg,
                          const float* __restrict__ bias,
                          const float* __restrict__ res,    // nullable, added pre-LN
                          const float* __restrict__ lng,
                          const float* __restrict__ lnb,
                          const float* __restrict__ skip,   // nullable, added post-ELU
                          float* __restrict__ out)
{
    const int n = blockIdx.x, t = threadIdx.x;
    const int i = n * DM + t;
    float v = agg[i] + bias[t];
    if (res) v += res[i];

    __shared__ float red[2];
    const int lane = t & 63, wave = t >> 6;

    float s = v;
#pragma unroll
    for (int off = 32; off; off >>= 1) s += __shfl_down(s, off);
    if (lane == 0) red[wave] = s;
    __syncthreads();
    float mean = (red[0] + red[1]) * (1.f / DM);
    __syncthreads();

    float dv = v - mean;
    float s2 = dv * dv;
#pragma unroll
    for (int off = 32; off; off >>= 1) s2 += __shfl_down(s2, off);
    if (lane == 0) red[wave] = s2;
    __syncthreads();
    float var = (red[0] + red[1]) * (1.f / DM);

    float y = dv * rsqrtf(var + EPS) * lng[t] + lnb[t];
    y = y > 0.f ? y : expm1f(y);   // ELU
    if (skip) y += skip[i];
    out[i] = y;
}

// ---------------------------------------------------------------------------
// Global mean pool (accumulate): sums[batch[n], c] += emb[n, c]; cnt[b] += 1
// ---------------------------------------------------------------------------
__global__ void pool_kernel(const float* __restrict__ emb,
                            const int* __restrict__ batch,
                            float* __restrict__ sums,
                            float* __restrict__ cnt)
{
    const int n = blockIdx.x, t = threadIdx.x;
    const int b = batch[n];
    atomicAdd(&sums[b * DM + t], emb[n * DM + t]);
    if (t == 0) atomicAdd(&cnt[b], 1.0f);
}

// ---------------------------------------------------------------------------
// Head: graph_emb = sums/cnt; logits = ge @ Wfc + bfc; BatchNorm over graphs.
// single block, 1024 threads.
// ---------------------------------------------------------------------------
__global__ void head_kernel(const float* __restrict__ sums,
                            const float* __restrict__ cnt,
                            const float* __restrict__ Wfc,
                            const float* __restrict__ bfc,
                            const float* __restrict__ bn_g,
                            const float* __restrict__ bn_b,
                            float* __restrict__ out)
{
    __shared__ float ge[NG * DM];
    __shared__ float lg[NG * OUTC];
    __shared__ float mu[OUTC], inv[OUTC];
    const int t = threadIdx.x;

    for (int i = t; i < NG * DM; i += blockDim.x) {
        int g = i >> 7;
        ge[i] = sums[i] / fmaxf(cnt[g], 1.0f);
    }
    __syncthreads();

    for (int i = t; i < NG * OUTC; i += blockDim.x) {
        int g = i >> 5, o = i & (OUTC - 1);
        float acc = bfc[o];
#pragma unroll
        for (int k = 0; k < DM; ++k) acc += ge[g * DM + k] * Wfc[k * OUTC + o];
        lg[i] = acc;
    }
    __syncthreads();

    if (t < OUTC) {
        float s = 0.f;
        for (int g = 0; g < NG; ++g) s += lg[g * OUTC + t];
        float m = s * (1.f / NG);
        float v = 0.f;
        for (int g = 0; g < NG; ++g) { float d = lg[g * OUTC + t] - m; v += d * d; }
        v *= (1.f / NG);
        mu[t] = m;
        inv[t] = rsqrtf(v + EPS) * bn_g[t];
    }
    __syncthreads();

    for (int i = t; i < NG * OUTC; i += blockDim.x) {
        int o = i & (OUTC - 1);
        out[i] = (lg[i] - mu[o]) * inv[o] + bn_b[o];
    }
}

// ---------------------------------------------------------------------------
extern "C" void kernel_launch(void* const* d_in, const int* in_sizes, int n_in,
                              void* d_out, int out_size, void* d_ws, size_t ws_size,
                              hipStream_t stream)
{
    const float* x     = (const float*)d_in[0];
    const int*   ei    = (const int*)  d_in[1];
    const int*   batch = (const int*)  d_in[2];
    const float* W1    = (const float*)d_in[3];
    const float* as1   = (const float*)d_in[4];
    const float* ad1   = (const float*)d_in[5];
    const float* b1    = (const float*)d_in[6];
    const float* ln1g  = (const float*)d_in[7];
    const float* ln1b  = (const float*)d_in[8];
    const float* Wskip = (const float*)d_in[9];
    const float* bskip = (const float*)d_in[10];
    const float* W2    = (const float*)d_in[11];
    const float* as2   = (const float*)d_in[12];
    const float* ad2   = (const float*)d_in[13];
    const float* b2    = (const float*)d_in[14];
    const float* ln2g  = (const float*)d_in[15];
    const float* ln2b  = (const float*)d_in[16];
    const float* Wfc   = (const float*)d_in[17];
    const float* bfc   = (const float*)d_in[18];
    const float* bng   = (const float*)d_in[19];
    const float* bnb   = (const float*)d_in[20];

    const int N  = in_sizes[2];
    const int E  = in_sizes[1] / 2;
    const int Ep = E + N;

    size_t off = 0;
    auto alloc = [&](size_t bytes) -> float* {
        float* p = (float*)((char*)d_ws + off);
        off += (bytes + 255) & ~(size_t)255;
        return p;
    };
    float* Hbuf  = alloc((size_t)N * DM * 4);          // h1, then h2
    float* Buf1  = alloc((size_t)N * DM * 4);          // agg1 -> x1 (kept for residual)
    float* Buf2  = alloc((size_t)N * DM * 4);          // skip -> agg2 -> emb
    float* ebuf  = alloc((size_t)Ep * NHEAD * 4);      // per-edge exp(e)
    float* denom = alloc((size_t)N * NHEAD * 4);
    float* asrc  = alloc((size_t)N * NHEAD * 4);
    float* adst  = alloc((size_t)N * NHEAD * 4);
    float* sums  = alloc((size_t)(NG * DM + NG) * 4);  // sums | cnt contiguous
    float* cnt   = sums + NG * DM;

    const int eb1 = (Ep * NHEAD + 255) / 256;
    const int eb2 = (int)(((long long)Ep * DM + 255) / 256);

    // ---- layer 1 ----
    gemm_attn_kernel<<<N, DM, 0, stream>>>(x, W1, Wskip, bskip, as1, ad1,
                                           Hbuf, Buf2, asrc, adst);
    hipMemsetAsync(denom, 0, (size_t)N * NHEAD * 4, stream);
    hipMemsetAsync(Buf1, 0, (size_t)N * DM * 4, stream);
    edge_logits_kernel<<<eb1, 256, 0, stream>>>(ei, E, Ep, asrc, adst, ebuf, denom);
    edge_msg_kernel<<<eb2, 256, 0, stream>>>(ei, E, Ep, Hbuf, ebuf, denom, Buf1);
    ln_kernel<<<N, DM, 0, stream>>>(Buf1, b1, nullptr, ln1g, ln1b, Buf2, Buf1);

    // ---- layer 2 ----
    gemm_attn_kernel<<<N, DM, 0, stream>>>(Buf1, W2, nullptr, nullptr, as2, ad2,
                                           Hbuf, nullptr, asrc, adst);
    hipMemsetAsync(denom, 0, (size_t)N * NHEAD * 4, stream);
    hipMemsetAsync(Buf2, 0, (size_t)N * DM * 4, stream);
    edge_logits_kernel<<<eb1, 256, 0, stream>>>(ei, E, Ep, asrc, adst, ebuf, denom);
    edge_msg_kernel<<<eb2, 256, 0, stream>>>(ei, E, Ep, Hbuf, ebuf, denom, Buf2);
    ln_kernel<<<N, DM, 0, stream>>>(Buf2, b2, Buf1, ln2g, ln2b, nullptr, Buf2);

    // ---- pool + head ----
    hipMemsetAsync(sums, 0, (size_t)(NG * DM + NG) * 4, stream);
    pool_kernel<<<N, DM, 0, stream>>>(Buf2, batch, sums, cnt);
    head_kernel<<<1, 1024, 0, stream>>>(sums, cnt, Wfc, bfc, bng, bnb, (float*)d_out);
}